// Round 10
// baseline (15593.266 us; speedup 1.0000x reference)
//
#include <hip/hip_runtime.h>
#include <hip/hip_bf16.h>
#include <cstdint>
#include <cstddef>

#define V_SZ 32000
#define E_SZ 512
#define U_SZ 1024
#define B_SZ 4
#define S_SZ 2048
#define NGRU 128      // GRU roles: 128 WGs x 256 thr = 512 waves; wave owns 2 h-cols
#define NTILES 16000  // logits tiles: 64 (tblk,b) groups x 250 n-tiles
#define GRID_FUSED 1152

typedef _Float16 f16;
typedef _Float16 f16x2 __attribute__((ext_vector_type(2)));
typedef _Float16 f16x8 __attribute__((ext_vector_type(8)));
typedef _Float16 f16x4 __attribute__((ext_vector_type(4)));
typedef float    f32x4 __attribute__((ext_vector_type(4)));
typedef unsigned long long u64;

__device__ __forceinline__ void async_copy16(const void* g, void* l) {
  __builtin_amdgcn_global_load_lds(
      (const __attribute__((address_space(1))) void*)g,
      (__attribute__((address_space(3))) void*)l, 16, 0, 0);
}

__device__ __forceinline__ f32x4 mfma16(f16x8 a, f16x8 b, f32x4 c) {
  return __builtin_amdgcn_mfma_f32_16x16x32_f16(a, b, c, 0, 0, 0);
}

// full-wave (64) sum via DPP; result valid in lane 63 only. Pure VALU.
__device__ __forceinline__ float wave_sum64(float v) {
  v += __int_as_float(__builtin_amdgcn_update_dpp(0, __float_as_int(v), 0x111, 0xf, 0xf, true)); // row_shr:1
  v += __int_as_float(__builtin_amdgcn_update_dpp(0, __float_as_int(v), 0x112, 0xf, 0xf, true)); // row_shr:2
  v += __int_as_float(__builtin_amdgcn_update_dpp(0, __float_as_int(v), 0x114, 0xf, 0xf, true)); // row_shr:4
  v += __int_as_float(__builtin_amdgcn_update_dpp(0, __float_as_int(v), 0x118, 0xf, 0xf, true)); // row_shr:8
  v += __int_as_float(__builtin_amdgcn_update_dpp(0, __float_as_int(v), 0x142, 0xa, 0xf, true)); // row_bcast:15
  v += __int_as_float(__builtin_amdgcn_update_dpp(0, __float_as_int(v), 0x143, 0xc, 0xf, true)); // row_bcast:31
  return v;
}

// ---------------- embedding gather + hi/lo fp16 split ----------------
__global__ void k_gather_split(const int* __restrict__ inputs, const float* __restrict__ emb,
                               f16* __restrict__ x_hi, f16* __restrict__ x_lo) {
  int m = blockIdx.x;                  // 8192 rows, m = b*2048 + s
  int row = inputs[m];
  const float* src = emb + (size_t)row * E_SZ;
  int j = threadIdx.x * 4;
  f32x4 v = *(const f32x4*)(src + j);
  f16x4 hi, lo;
#pragma unroll
  for (int q = 0; q < 4; ++q) {
    f16 h = (f16)v[q];
    hi[q] = h;
    lo[q] = (f16)((v[q] - (float)h) * 4096.0f);
  }
  *(f16x4*)(x_hi + (size_t)m * E_SZ + j) = hi;
  *(f16x4*)(x_lo + (size_t)m * E_SZ + j) = lo;
}

// ---------------- transpose [K][N] fp32 -> [N][K] fp16 ----------------
__global__ void k_transpose_split(const float* __restrict__ W, f16* __restrict__ Wt,
                                  int K, int N) {
  __shared__ float tile[32][33];
  int tx = threadIdx.x & 31, ty = threadIdx.x >> 5;   // 32 x 8
  int n0 = blockIdx.x * 32, k0 = blockIdx.y * 32;
#pragma unroll
  for (int i = 0; i < 4; ++i)
    tile[ty + 8 * i][tx] = W[(size_t)(k0 + ty + 8 * i) * N + n0 + tx];
  __syncthreads();
#pragma unroll
  for (int i = 0; i < 4; ++i)
    Wt[(size_t)(n0 + ty + 8 * i) * K + k0 + tx] = (f16)tile[tx][ty + 8 * i];
}

// ---------------- fp16 2-pass GEMM (xg only): C = (Ah+Al/4096)@Bt^T + bias -------
template<int K, bool REMAP>
__global__ __launch_bounds__(256, 2)
void k_gemm2s(const f16* __restrict__ Ah, const f16* __restrict__ Al,
              const f16* __restrict__ Bt, const float* __restrict__ bias,
              float* __restrict__ C, int N) {
  __shared__ f16 lds[2][3 * 4096];
  const int tid = threadIdx.x;
  const int lane = tid & 63;
  const int wave = tid >> 6;
  const int wm = wave >> 1, wn = wave & 1;
  const int m0 = blockIdx.y * 128;
  const int n0 = blockIdx.x * 128;

  auto stage = [&](int buf, int kk) {
#pragma unroll
    for (int i = 0; i < 6; ++i) {
      int g = i * 256 + tid;
      int tile = g >> 9;
      int idx = g & 511;
      int r = idx >> 2;
      int kg = (idx & 3) ^ ((r >> 1) & 3);
      const f16* src = (tile == 0) ? Ah : (tile == 1) ? Al : Bt;
      int row = (tile == 2) ? (n0 + r) : (m0 + r);
      const f16* gp = src + (size_t)row * K + kk + kg * 8;
      f16* lp = &lds[buf][(g & ~63) * 8];
      async_copy16(gp, lp);
    }
  };

  f32x4 accH[4][4] = {};
  f32x4 accL[4][4] = {};
  stage(0, 0);
  int buf = 0;
  for (int kk = 0; kk < K; kk += 32) {
    __syncthreads();
    if (kk + 32 < K) stage(buf ^ 1, kk + 32);
    const f16* base = &lds[buf][0];
    const int kg = lane >> 4;
    f16x8 bfr[4];
#pragma unroll
    for (int fn = 0; fn < 4; ++fn) {
      int r = wn * 64 + fn * 16 + (lane & 15);
      bfr[fn] = *(const f16x8*)(base + 2 * 4096 + r * 32 + ((kg ^ ((r >> 1) & 3)) * 8));
    }
#pragma unroll
    for (int fm = 0; fm < 4; ++fm) {
      int r = wm * 64 + fm * 16 + (lane & 15);
      int off = r * 32 + ((kg ^ ((r >> 1) & 3)) * 8);
      f16x8 ah = *(const f16x8*)(base + off);
      f16x8 al = *(const f16x8*)(base + 4096 + off);
#pragma unroll
      for (int fn = 0; fn < 4; ++fn) {
        accH[fm][fn] = mfma16(ah, bfr[fn], accH[fm][fn]);
        accL[fm][fn] = mfma16(al, bfr[fn], accL[fm][fn]);
      }
    }
    buf ^= 1;
  }
  const float inv = 1.0f / 4096.0f;
#pragma unroll
  for (int fn = 0; fn < 4; ++fn) {
    int col = n0 + wn * 64 + fn * 16 + (lane & 15);
    float bv = bias[col];
#pragma unroll
    for (int fm = 0; fm < 4; ++fm) {
      int row0 = m0 + wm * 64 + fm * 16 + ((lane >> 4) << 2);
#pragma unroll
      for (int j = 0; j < 4; ++j) {
        int row = row0 + j;
        float v = accH[fm][fn][j] + inv * accL[fm][fn][j] + bv;
        size_t orow = REMAP ? ((size_t)(row & (S_SZ - 1)) * B_SZ + (row >> 11))
                            : (size_t)row;
        C[orow * (size_t)N + col] = v;
      }
    }
  }
}

// ================= fused persistent kernel: GRU roles + logits-GEMM roles =========
// Role by ARRIVAL ticket (safe under any dispatch order): tickets 0..127 run the
// v8 GRU (7.25ms-proven body, setprio(1)); the rest steal logits tiles in
// ready-order via a tile ticket. Handshake: hs stores are relaxed agent 4B atomics
// (write-through to IC); at t%128==127 lane63 waits vmcnt(0) then relaxed
// fetch_add(cnt[tblk*4+b]); GEMM WG polls cnt[g]==512 (agent atomics = IC-coherent,
// immune to graph-replay-stale L2), then reg-stages A with sc0sc1 loads (bypass ->
// no stale hs lines), B via global_load_lds (stale lines hold identical bytes).
// Deadlock-free: GRU roles are running by construction and never wait on GEMM.

__device__ __forceinline__ void gru_role(int role, char* smem,
    const float* __restrict__ xg, const float* __restrict__ Wh,
    const float* __restrict__ bh, u64* __restrict__ h_ring,
    f16* __restrict__ hs_hi, f16* __restrict__ hs_lo, unsigned* __restrict__ cnt) {
  float (*Whs)[1028] = (float(*)[1028])smem;   // staging only (init), 32.9 KB
  const int tid = threadIdx.x;
  const int lane = tid & 63;
  const int wave = tid >> 6;
  const int u0 = role * 8;             // WG's 8 cols
  const int col0 = u0 + wave * 2;

  // ---- stage Wh into registers: Wreg order [z0,z1,r0,r1,h0,h1] ----
  f32x4 Wreg[6][4];
  for (int gate = 0; gate < 3; ++gate) {
    __syncthreads();
    for (int idx = tid; idx < 8 * 1024; idx += 256) {
      int j = idx & 7, k = idx >> 3;
      Whs[j][k] = Wh[(size_t)k * 3072 + gate * 1024 + u0 + j];
    }
    __syncthreads();
#pragma unroll
    for (int cj = 0; cj < 2; ++cj)
#pragma unroll
      for (int i = 0; i < 4; ++i)
        Wreg[gate * 2 + cj][i] = *(const f32x4*)&Whs[wave * 2 + cj][i * 256 + lane * 4];
  }
  __builtin_amdgcn_s_setprio(1);       // favor the recurrence over co-tenant GEMM waves

  const float bz0 = bh[col0],        bz1 = bh[col0 + 1];
  const float br0 = bh[1024 + col0], br1 = bh[1024 + col0 + 1];
  const float bq0 = bh[2048 + col0], bq1 = bh[2048 + col0 + 1];
  float hold0[4] = {0.f, 0.f, 0.f, 0.f};
  float hold1[4] = {0.f, 0.f, 0.f, 0.f};
  const u64 POIS = 0xFFFFFFFFFFFFFFFFull;

  u64 q[8];
  const u64* pbase;
  auto pollLoads = [&]() {
#pragma unroll
    for (int i = 0; i < 4; ++i) {
      q[2 * i]     = __hip_atomic_load(pbase + i * 128 + 2 * lane,
                                       __ATOMIC_RELAXED, __HIP_MEMORY_SCOPE_AGENT);
      q[2 * i + 1] = __hip_atomic_load(pbase + i * 128 + 2 * lane + 1,
                                       __ATOMIC_RELAXED, __HIP_MEMORY_SCOPE_AGENT);
    }
  };
  auto issue = [&](int slot, int row) {
    pbase = h_ring + ((size_t)slot * B_SZ + row) * 512;
    pollLoads();
  };
  float2 xzv[4], xrv[4], xhv[4];
  auto xgIssue = [&](int b2, int t2) {
    const float* p = xg + ((size_t)t2 * B_SZ + b2) * 3072 + col0;
    xzv[b2] = *(const float2*)p;
    xrv[b2] = *(const float2*)(p + 1024);
    xhv[b2] = *(const float2*)(p + 2048);
  };

  issue(0, 0);
  xgIssue(0, 0); xgIssue(1, 0); xgIssue(2, 0); xgIssue(3, 0);

  for (int t = 0; t < S_SZ; ++t) {
#pragma unroll
    for (int b = 0; b < 4; ++b) {
      const float2 xz = xzv[b], xr = xrv[b], xh = xhv[b];
      // peeled fast-path check (counted wait); retry is the rare path
      {
        bool ok = (q[0] != POIS) && (q[1] != POIS) && (q[2] != POIS) && (q[3] != POIS)
               && (q[4] != POIS) && (q[5] != POIS) && (q[6] != POIS) && (q[7] != POIS);
        if (!__all(ok)) {
          while (true) {
            __builtin_amdgcn_s_sleep(1);
            pollLoads();
            bool ok2 = (q[0] != POIS) && (q[1] != POIS) && (q[2] != POIS) && (q[3] != POIS)
                    && (q[4] != POIS) && (q[5] != POIS) && (q[6] != POIS) && (q[7] != POIS);
            if (__all(ok2)) break;
          }
        }
      }
      float hp[16];
#pragma unroll
      for (int j2 = 0; j2 < 8; ++j2) {
        hp[2 * j2]     = __uint_as_float((unsigned int)q[j2]);
        hp[2 * j2 + 1] = __uint_as_float((unsigned int)(q[j2] >> 32));
      }
      float a6[6];
#pragma unroll
      for (int c = 0; c < 6; ++c) {
        float v = 0.0f;
#pragma unroll
        for (int i = 0; i < 4; ++i)
#pragma unroll
          for (int qq = 0; qq < 4; ++qq)
            v += Wreg[c][i][qq] * hp[4 * i + qq];
        a6[c] = v;
      }
      float s0 = wave_sum64(a6[0]), s1 = wave_sum64(a6[1]), s2 = wave_sum64(a6[2]);
      float s3 = wave_sum64(a6[3]), s4 = wave_sum64(a6[4]), s5 = wave_sum64(a6[5]);

      // issue next-slice polls + next-step xg BEFORE stores (drain hygiene, v8)
      asm volatile("" ::: "memory");
      {
        const int nb = (b + 1) & 3;
        const int nt = (b == 3) ? (t + 1) : t;
        issue(nt & 7, nb);
        const int tp1 = (t + 1 < S_SZ) ? (t + 1) : (S_SZ - 1);
        xgIssue(b, tp1);
      }
      asm volatile("" ::: "memory");

      if (lane == 63) {
        __hip_atomic_store(h_ring + ((size_t)((t + 4) & 7) * B_SZ + b) * 512 + (col0 >> 1),
                           POIS, __ATOMIC_RELAXED, __HIP_MEMORY_SCOPE_AGENT);
        float z0 = __builtin_amdgcn_rcpf(1.0f + __expf(-(xz.x + s0 + bz0)));
        float z1 = __builtin_amdgcn_rcpf(1.0f + __expf(-(xz.y + s1 + bz1)));
        float r0 = __builtin_amdgcn_rcpf(1.0f + __expf(-(xr.x + s2 + br0)));
        float r1 = __builtin_amdgcn_rcpf(1.0f + __expf(-(xr.y + s3 + br1)));
        float a0 = xh.x + r0 * (s4 + bq0);
        float a1 = xh.y + r1 * (s5 + bq1);
        float e0 = __expf(-2.0f * fabsf(a0));
        float e1 = __expf(-2.0f * fabsf(a1));
        float hc0 = copysignf((1.0f - e0) * __builtin_amdgcn_rcpf(1.0f + e0), a0);
        float hc1 = copysignf((1.0f - e1) * __builtin_amdgcn_rcpf(1.0f + e1), a1);
        float h0 = z0 * hold0[b] + (1.0f - z0) * hc0;
        float h1 = z1 * hold1[b] + (1.0f - z1) * hc1;
        hold0[b] = h0; hold1[b] = h1;
        u64 hv = ((u64)__float_as_uint(h1) << 32) | (u64)__float_as_uint(h0);
        __hip_atomic_store(h_ring + ((size_t)((t + 1) & 7) * B_SZ + b) * 512 + (col0 >> 1),
                           hv, __ATOMIC_RELAXED, __HIP_MEMORY_SCOPE_AGENT);
        // hs output: write-through 4B atomics (IC-visible for in-kernel consumer)
        size_t hidx = ((size_t)b * S_SZ + t) * U_SZ + col0;
        f16 h0h = (f16)h0, h1h = (f16)h1;
        f16x2 hi2; hi2[0] = h0h; hi2[1] = h1h;
        f16x2 lo2;
        lo2[0] = (f16)((h0 - (float)h0h) * 4096.0f);
        lo2[1] = (f16)((h1 - (float)h1h) * 4096.0f);
        unsigned uhi, ulo;
        __builtin_memcpy(&uhi, &hi2, 4);
        __builtin_memcpy(&ulo, &lo2, 4);
        __hip_atomic_store((unsigned*)(hs_hi + hidx), uhi,
                           __ATOMIC_RELAXED, __HIP_MEMORY_SCOPE_AGENT);
        __hip_atomic_store((unsigned*)(hs_lo + hidx), ulo,
                           __ATOMIC_RELAXED, __HIP_MEMORY_SCOPE_AGENT);
        if ((t & 127) == 127) {        // block boundary: release hs block (proven pattern)
          asm volatile("s_waitcnt vmcnt(0)" ::: "memory");
          __hip_atomic_fetch_add(&cnt[(((unsigned)t >> 7) << 2) | (unsigned)b], 1u,
                                 __ATOMIC_RELAXED, __HIP_MEMORY_SCOPE_AGENT);
        }
      }
    }
  }
}

__device__ __forceinline__ void gemm_role(char* smem, int* sh_tile,
    const f16* __restrict__ Ah, const f16* __restrict__ Al,
    const f16* __restrict__ Bt, const float* __restrict__ bd,
    float* __restrict__ out, unsigned* __restrict__ cnt, unsigned* __restrict__ ttix) {
  f16 (*lds)[3 * 4096] = (f16(*)[3 * 4096])smem;   // 48 KB
  const int tid = threadIdx.x;
  const int lane = tid & 63;
  const int wave = tid >> 6;
  const int wm = wave >> 1, wn = wave & 1;

  for (;;) {
    __syncthreads();                   // protect sh_tile reuse
    if (tid == 0)
      *sh_tile = (int)__hip_atomic_fetch_add(ttix, 1u, __ATOMIC_RELAXED,
                                             __HIP_MEMORY_SCOPE_AGENT);
    __syncthreads();
    const int tile = *sh_tile;
    if (tile >= NTILES) break;
    const int g = tile / 250;
    const int n0 = (tile % 250) * 128;
    if (tid == 0) {                    // ready-poll (agent atomic = IC-coherent)
      while (__hip_atomic_load(&cnt[g], __ATOMIC_RELAXED, __HIP_MEMORY_SCOPE_AGENT) < 512u)
        __builtin_amdgcn_s_sleep(10);
    }
    __syncthreads();
    const int m0 = (g & 3) * S_SZ + (g >> 2) * 128;

    f32x4 accH[4][4] = {};
    f32x4 accL[4][4] = {};
    f32x4 areg[4];
    auto issueA = [&](int kk) {        // sc0sc1 reg-stage (bypass -> never stale)
#pragma unroll
      for (int i = 0; i < 4; ++i) {
        int gg = i * 256 + tid;
        int idx = gg & 511, r = idx >> 2;
        int kg = (idx & 3) ^ ((r >> 1) & 3);
        const f16* src = (gg >> 9) ? Al : Ah;
        const f16* gp = src + (size_t)(m0 + r) * 1024 + kk + kg * 8;
        asm volatile("global_load_dwordx4 %0, %1, off sc0 sc1"
                     : "=&v"(areg[i]) : "v"(gp) : "memory");
      }
    };
    auto issueB = [&](int buf, int kk) {
#pragma unroll
      for (int i = 4; i < 6; ++i) {
        int gg = i * 256 + tid;
        int idx = gg & 511, r = idx >> 2;
        int kg = (idx & 3) ^ ((r >> 1) & 3);
        const f16* gp = Bt + (size_t)(n0 + r) * 1024 + kk + kg * 8;
        f16* lp = &lds[buf][(gg & ~63) * 8];
        async_copy16(gp, lp);
      }
    };
    auto writeA = [&](int buf) {
#pragma unroll
      for (int i = 0; i < 4; ++i) {
        int gg = i * 256 + tid;
        *(f32x4*)&lds[buf][gg * 8] = areg[i];
      }
    };

    issueA(0); issueB(0, 0);
    asm volatile("s_waitcnt vmcnt(2)" ::: "memory");   // A retired; B may ride
    writeA(0);
    int buf = 0;
    for (int kk = 0; kk < 1024; kk += 32) {
      __syncthreads();                 // buf ready (B via vmcnt at barrier, A via lgkm)
      const bool more = (kk + 32 < 1024);
      if (more) { issueA(kk + 32); issueB(buf ^ 1, kk + 32); }
      const f16* base = &lds[buf][0];
      const int kgl = lane >> 4;
      f16x8 bfr[4];
#pragma unroll
      for (int fn = 0; fn < 4; ++fn) {
        int r = wn * 64 + fn * 16 + (lane & 15);
        bfr[fn] = *(const f16x8*)(base + 2 * 4096 + r * 32 + ((kgl ^ ((r >> 1) & 3)) * 8));
      }
#pragma unroll
      for (int fm = 0; fm < 4; ++fm) {
        int r = wm * 64 + fm * 16 + (lane & 15);
        int off = r * 32 + ((kgl ^ ((r >> 1) & 3)) * 8);
        f16x8 ah = *(const f16x8*)(base + off);
        f16x8 al = *(const f16x8*)(base + 4096 + off);
#pragma unroll
        for (int fn = 0; fn < 4; ++fn) {
          accH[fm][fn] = mfma16(ah, bfr[fn], accH[fm][fn]);
          accL[fm][fn] = mfma16(al, bfr[fn], accL[fm][fn]);
        }
      }
      if (more) {
        asm volatile("s_waitcnt vmcnt(2)" ::: "memory");  // this iter's A retired
        writeA(buf ^ 1);
      }
      buf ^= 1;
    }
    const float inv = 1.0f / 4096.0f;
#pragma unroll
    for (int fn = 0; fn < 4; ++fn) {
      int col = n0 + wn * 64 + fn * 16 + (lane & 15);
      float bv = bd[col];
#pragma unroll
      for (int fm = 0; fm < 4; ++fm) {
        int row0 = m0 + wm * 64 + fm * 16 + ((lane >> 4) << 2);
#pragma unroll
        for (int j = 0; j < 4; ++j)
          out[(size_t)(row0 + j) * V_SZ + col] = accH[fm][fn][j] + inv * accL[fm][fn][j] + bv;
      }
    }
  }
}

__global__ __launch_bounds__(256, 2)
void k_fused(const float* __restrict__ xg, const float* __restrict__ Wh,
             const float* __restrict__ bh, u64* __restrict__ h_ring,
             f16* __restrict__ hs_hi, f16* __restrict__ hs_lo,
             const f16* __restrict__ Wd_t, const float* __restrict__ bd,
             float* __restrict__ out, unsigned* __restrict__ cnt,
             unsigned* __restrict__ tix) {
  __shared__ __align__(16) char smem[49152];
  __shared__ int sh_role;
  __shared__ int sh_tile;
  if (threadIdx.x == 0)
    sh_role = (int)__hip_atomic_fetch_add(&tix[0], 1u, __ATOMIC_RELAXED,
                                          __HIP_MEMORY_SCOPE_AGENT);
  __syncthreads();
  const int role = sh_role;
  if (role < NGRU)
    gru_role(role, smem, xg, Wh, bh, h_ring, hs_hi, hs_lo, cnt);
  else
    gemm_role(smem, &sh_tile, hs_hi, hs_lo, Wd_t, bd, out, cnt, &tix[1]);
}

// ---------------- launch ----------------
extern "C" void kernel_launch(void* const* d_in, const int* in_sizes, int n_in,
                              void* d_out, int out_size, void* d_ws, size_t ws_size,
                              hipStream_t stream) {
  const int*   inputs = (const int*)d_in[0];
  const float* emb    = (const float*)d_in[1];
  const float* Wx     = (const float*)d_in[2];
  const float* Wh     = (const float*)d_in[3];
  const float* bx     = (const float*)d_in[4];
  const float* bh     = (const float*)d_in[5];
  const float* Wd     = (const float*)d_in[6];
  const float* bd     = (const float*)d_in[7];
  float* out = (float*)d_out;

  char* ws = (char*)d_ws;
  // layout (bytes), all 256-aligned
  f16*   x_hi  = (f16*)(ws + 0);            //  8,388,608
  f16*   x_lo  = (f16*)(ws + 8388608);      //  8,388,608
  f16*   Wx_t  = (f16*)(ws + 16777216);     //  3,145,728  [3072][512]
  f16*   Wd_t  = (f16*)(ws + 19922944);     // 65,536,000  [32000][1024]
  f16*   hs_hi = (f16*)(ws + 85458944);     // 16,777,216  [B*S][1024]
  f16*   hs_lo = (f16*)(ws + 102236160);    // 16,777,216
  float* xg    = (float*)(ws + 119013376);  // 100,663,296 [S][B][3072]
  u64*   h_ring = (u64*)(ws + 219676672);   // 131,072     [8][4][1024] fp32
  unsigned* cnt = (unsigned*)(ws + 219807744);  // 256  [64]
  unsigned* tix = (unsigned*)(ws + 219808000);  // 8    [role, tile]

  // per-call init (graph-replay safe): ring slot0=zeros, slots1-7=-NaN; cnt/tix=0
  hipMemsetAsync(ws + 219676672, 0x00, 16384, stream);
  hipMemsetAsync(ws + 219676672 + 16384, 0xFF, 114688, stream);
  hipMemsetAsync(ws + 219807744, 0x00, 512, stream);

  k_gather_split<<<B_SZ * S_SZ, 128, 0, stream>>>(inputs, emb, x_hi, x_lo);
  k_transpose_split<<<dim3(3072 / 32, 512 / 32), 256, 0, stream>>>(Wx, Wx_t, 512, 3072);
  k_transpose_split<<<dim3(V_SZ / 32, 1024 / 32), 256, 0, stream>>>(Wd, Wd_t, 1024, V_SZ);
  k_gemm2s<512, true><<<dim3(3072 / 128, 8192 / 128), 256, 0, stream>>>(
      x_hi, x_lo, Wx_t, bx, xg, 3072);
  k_fused<<<GRID_FUSED, 256, 0, stream>>>(xg, Wh, bh, h_ring, hs_hi, hs_lo,
                                          Wd_t, bd, out, cnt, tix);
}

// Round 11
// 9002.428 us; speedup vs baseline: 1.7321x; 1.7321x over previous
//
#include <hip/hip_runtime.h>
#include <hip/hip_bf16.h>
#include <cstdint>
#include <cstddef>

#define V_SZ 32000
#define E_SZ 512
#define U_SZ 1024
#define B_SZ 4
#define S_SZ 2048
#define NGRU 128      // GRU roles: 128 WGs x 256 thr = 512 waves; wave owns 2 h-cols
#define NTILES 16000  // logits tiles: 64 (tblk,b) groups x 250 n-tiles
#define GRID_FUSED 256  // == CU count: 1 WG/CU, GRU and GEMM spatially partitioned

typedef _Float16 f16;
typedef _Float16 f16x2 __attribute__((ext_vector_type(2)));
typedef _Float16 f16x8 __attribute__((ext_vector_type(8)));
typedef _Float16 f16x4 __attribute__((ext_vector_type(4)));
typedef float    f32x4 __attribute__((ext_vector_type(4)));
typedef unsigned long long u64;

__device__ __forceinline__ void async_copy16(const void* g, void* l) {
  __builtin_amdgcn_global_load_lds(
      (const __attribute__((address_space(1))) void*)g,
      (__attribute__((address_space(3))) void*)l, 16, 0, 0);
}

__device__ __forceinline__ f32x4 mfma16(f16x8 a, f16x8 b, f32x4 c) {
  return __builtin_amdgcn_mfma_f32_16x16x32_f16(a, b, c, 0, 0, 0);
}

// full-wave (64) sum via DPP; result valid in lane 63 only. Pure VALU.
__device__ __forceinline__ float wave_sum64(float v) {
  v += __int_as_float(__builtin_amdgcn_update_dpp(0, __float_as_int(v), 0x111, 0xf, 0xf, true)); // row_shr:1
  v += __int_as_float(__builtin_amdgcn_update_dpp(0, __float_as_int(v), 0x112, 0xf, 0xf, true)); // row_shr:2
  v += __int_as_float(__builtin_amdgcn_update_dpp(0, __float_as_int(v), 0x114, 0xf, 0xf, true)); // row_shr:4
  v += __int_as_float(__builtin_amdgcn_update_dpp(0, __float_as_int(v), 0x118, 0xf, 0xf, true)); // row_shr:8
  v += __int_as_float(__builtin_amdgcn_update_dpp(0, __float_as_int(v), 0x142, 0xa, 0xf, true)); // row_bcast:15
  v += __int_as_float(__builtin_amdgcn_update_dpp(0, __float_as_int(v), 0x143, 0xc, 0xf, true)); // row_bcast:31
  return v;
}

// ---------------- embedding gather + hi/lo fp16 split ----------------
__global__ void k_gather_split(const int* __restrict__ inputs, const float* __restrict__ emb,
                               f16* __restrict__ x_hi, f16* __restrict__ x_lo) {
  int m = blockIdx.x;                  // 8192 rows, m = b*2048 + s
  int row = inputs[m];
  const float* src = emb + (size_t)row * E_SZ;
  int j = threadIdx.x * 4;
  f32x4 v = *(const f32x4*)(src + j);
  f16x4 hi, lo;
#pragma unroll
  for (int q = 0; q < 4; ++q) {
    f16 h = (f16)v[q];
    hi[q] = h;
    lo[q] = (f16)((v[q] - (float)h) * 4096.0f);
  }
  *(f16x4*)(x_hi + (size_t)m * E_SZ + j) = hi;
  *(f16x4*)(x_lo + (size_t)m * E_SZ + j) = lo;
}

// ---------------- transpose [K][N] fp32 -> [N][K] fp16 ----------------
__global__ void k_transpose_split(const float* __restrict__ W, f16* __restrict__ Wt,
                                  int K, int N) {
  __shared__ float tile[32][33];
  int tx = threadIdx.x & 31, ty = threadIdx.x >> 5;   // 32 x 8
  int n0 = blockIdx.x * 32, k0 = blockIdx.y * 32;
#pragma unroll
  for (int i = 0; i < 4; ++i)
    tile[ty + 8 * i][tx] = W[(size_t)(k0 + ty + 8 * i) * N + n0 + tx];
  __syncthreads();
#pragma unroll
  for (int i = 0; i < 4; ++i)
    Wt[(size_t)(n0 + ty + 8 * i) * K + k0 + tx] = (f16)tile[tx][ty + 8 * i];
}

// ---------------- fp16 2-pass GEMM (xg only): C = (Ah+Al/4096)@Bt^T + bias -------
template<int K, bool REMAP>
__global__ __launch_bounds__(256, 2)
void k_gemm2s(const f16* __restrict__ Ah, const f16* __restrict__ Al,
              const f16* __restrict__ Bt, const float* __restrict__ bias,
              float* __restrict__ C, int N) {
  __shared__ f16 lds[2][3 * 4096];
  const int tid = threadIdx.x;
  const int lane = tid & 63;
  const int wave = tid >> 6;
  const int wm = wave >> 1, wn = wave & 1;
  const int m0 = blockIdx.y * 128;
  const int n0 = blockIdx.x * 128;

  auto stage = [&](int buf, int kk) {
#pragma unroll
    for (int i = 0; i < 6; ++i) {
      int g = i * 256 + tid;
      int tile = g >> 9;
      int idx = g & 511;
      int r = idx >> 2;
      int kg = (idx & 3) ^ ((r >> 1) & 3);
      const f16* src = (tile == 0) ? Ah : (tile == 1) ? Al : Bt;
      int row = (tile == 2) ? (n0 + r) : (m0 + r);
      const f16* gp = src + (size_t)row * K + kk + kg * 8;
      f16* lp = &lds[buf][(g & ~63) * 8];
      async_copy16(gp, lp);
    }
  };

  f32x4 accH[4][4] = {};
  f32x4 accL[4][4] = {};
  stage(0, 0);
  int buf = 0;
  for (int kk = 0; kk < K; kk += 32) {
    __syncthreads();
    if (kk + 32 < K) stage(buf ^ 1, kk + 32);
    const f16* base = &lds[buf][0];
    const int kg = lane >> 4;
    f16x8 bfr[4];
#pragma unroll
    for (int fn = 0; fn < 4; ++fn) {
      int r = wn * 64 + fn * 16 + (lane & 15);
      bfr[fn] = *(const f16x8*)(base + 2 * 4096 + r * 32 + ((kg ^ ((r >> 1) & 3)) * 8));
    }
#pragma unroll
    for (int fm = 0; fm < 4; ++fm) {
      int r = wm * 64 + fm * 16 + (lane & 15);
      int off = r * 32 + ((kg ^ ((r >> 1) & 3)) * 8);
      f16x8 ah = *(const f16x8*)(base + off);
      f16x8 al = *(const f16x8*)(base + 4096 + off);
#pragma unroll
      for (int fn = 0; fn < 4; ++fn) {
        accH[fm][fn] = mfma16(ah, bfr[fn], accH[fm][fn]);
        accL[fm][fn] = mfma16(al, bfr[fn], accL[fm][fn]);
      }
    }
    buf ^= 1;
  }
  const float inv = 1.0f / 4096.0f;
#pragma unroll
  for (int fn = 0; fn < 4; ++fn) {
    int col = n0 + wn * 64 + fn * 16 + (lane & 15);
    float bv = bias[col];
#pragma unroll
    for (int fm = 0; fm < 4; ++fm) {
      int row0 = m0 + wm * 64 + fm * 16 + ((lane >> 4) << 2);
#pragma unroll
      for (int j = 0; j < 4; ++j) {
        int row = row0 + j;
        float v = accH[fm][fn][j] + inv * accL[fm][fn][j] + bv;
        size_t orow = REMAP ? ((size_t)(row & (S_SZ - 1)) * B_SZ + (row >> 11))
                            : (size_t)row;
        C[orow * (size_t)N + col] = v;
      }
    }
  }
}

// ================= fused persistent kernel: GRU roles + logits-GEMM roles =========
// grid = 256 = CU count -> 1 WG/CU, co-resident: GRU roles (tickets 0..127) own 128
// CUs with ZERO SIMD co-tenancy (round 10's regression cause); 128 GEMM workers own
// the other 128 CUs and steal tiles in ready-order. Handshake (round-10-proven):
// hs = relaxed agent 4B atomic stores (IC write-through); at t%128==127 lane63
// vmcnt(0) + fetch_add(cnt); worker polls cnt[g]==512, reg-stages A via sc0sc1
// (bypass -> no stale L2), B via global_load_lds (replay-stale lines = same bytes).
// Deadlock-free: GRU roles run by construction, never wait on GEMM state.

__device__ __forceinline__ void gru_role(int role, char* smem,
    const float* __restrict__ xg, const float* __restrict__ Wh,
    const float* __restrict__ bh, u64* __restrict__ h_ring,
    f16* __restrict__ hs_hi, f16* __restrict__ hs_lo, unsigned* __restrict__ cnt) {
  float (*Whs)[1028] = (float(*)[1028])smem;   // staging only (init), 32.9 KB
  const int tid = threadIdx.x;
  const int lane = tid & 63;
  const int wave = tid >> 6;
  const int u0 = role * 8;             // WG's 8 cols
  const int col0 = u0 + wave * 2;

  // ---- stage Wh into registers: Wreg order [z0,z1,r0,r1,h0,h1] ----
  f32x4 Wreg[6][4];
  for (int gate = 0; gate < 3; ++gate) {
    __syncthreads();
    for (int idx = tid; idx < 8 * 1024; idx += 256) {
      int j = idx & 7, k = idx >> 3;
      Whs[j][k] = Wh[(size_t)k * 3072 + gate * 1024 + u0 + j];
    }
    __syncthreads();
#pragma unroll
    for (int cj = 0; cj < 2; ++cj)
#pragma unroll
      for (int i = 0; i < 4; ++i)
        Wreg[gate * 2 + cj][i] = *(const f32x4*)&Whs[wave * 2 + cj][i * 256 + lane * 4];
  }
  __builtin_amdgcn_s_setprio(1);       // belt-and-braces (no co-tenant expected now)

  const float bz0 = bh[col0],        bz1 = bh[col0 + 1];
  const float br0 = bh[1024 + col0], br1 = bh[1024 + col0 + 1];
  const float bq0 = bh[2048 + col0], bq1 = bh[2048 + col0 + 1];
  float hold0[4] = {0.f, 0.f, 0.f, 0.f};
  float hold1[4] = {0.f, 0.f, 0.f, 0.f};
  const u64 POIS = 0xFFFFFFFFFFFFFFFFull;

  u64 q[8];
  const u64* pbase;
  auto pollLoads = [&]() {
#pragma unroll
    for (int i = 0; i < 4; ++i) {
      q[2 * i]     = __hip_atomic_load(pbase + i * 128 + 2 * lane,
                                       __ATOMIC_RELAXED, __HIP_MEMORY_SCOPE_AGENT);
      q[2 * i + 1] = __hip_atomic_load(pbase + i * 128 + 2 * lane + 1,
                                       __ATOMIC_RELAXED, __HIP_MEMORY_SCOPE_AGENT);
    }
  };
  auto issue = [&](int slot, int row) {
    pbase = h_ring + ((size_t)slot * B_SZ + row) * 512;
    pollLoads();
  };
  float2 xzv[4], xrv[4], xhv[4];
  auto xgIssue = [&](int b2, int t2) {
    const float* p = xg + ((size_t)t2 * B_SZ + b2) * 3072 + col0;
    xzv[b2] = *(const float2*)p;
    xrv[b2] = *(const float2*)(p + 1024);
    xhv[b2] = *(const float2*)(p + 2048);
  };

  issue(0, 0);
  xgIssue(0, 0); xgIssue(1, 0); xgIssue(2, 0); xgIssue(3, 0);

  for (int t = 0; t < S_SZ; ++t) {
#pragma unroll
    for (int b = 0; b < 4; ++b) {
      const float2 xz = xzv[b], xr = xrv[b], xh = xhv[b];
      // peeled fast-path check (counted wait); retry is the rare path
      {
        bool ok = (q[0] != POIS) && (q[1] != POIS) && (q[2] != POIS) && (q[3] != POIS)
               && (q[4] != POIS) && (q[5] != POIS) && (q[6] != POIS) && (q[7] != POIS);
        if (!__all(ok)) {
          while (true) {
            __builtin_amdgcn_s_sleep(1);
            pollLoads();
            bool ok2 = (q[0] != POIS) && (q[1] != POIS) && (q[2] != POIS) && (q[3] != POIS)
                    && (q[4] != POIS) && (q[5] != POIS) && (q[6] != POIS) && (q[7] != POIS);
            if (__all(ok2)) break;
          }
        }
      }
      float hp[16];
#pragma unroll
      for (int j2 = 0; j2 < 8; ++j2) {
        hp[2 * j2]     = __uint_as_float((unsigned int)q[j2]);
        hp[2 * j2 + 1] = __uint_as_float((unsigned int)(q[j2] >> 32));
      }
      float a6[6];
#pragma unroll
      for (int c = 0; c < 6; ++c) {
        float v = 0.0f;
#pragma unroll
        for (int i = 0; i < 4; ++i)
#pragma unroll
          for (int qq = 0; qq < 4; ++qq)
            v += Wreg[c][i][qq] * hp[4 * i + qq];
        a6[c] = v;
      }
      float s0 = wave_sum64(a6[0]), s1 = wave_sum64(a6[1]), s2 = wave_sum64(a6[2]);
      float s3 = wave_sum64(a6[3]), s4 = wave_sum64(a6[4]), s5 = wave_sum64(a6[5]);

      // issue next-slice polls + next-step xg BEFORE stores (drain hygiene, v8)
      asm volatile("" ::: "memory");
      {
        const int nb = (b + 1) & 3;
        const int nt = (b == 3) ? (t + 1) : t;
        issue(nt & 7, nb);
        const int tp1 = (t + 1 < S_SZ) ? (t + 1) : (S_SZ - 1);
        xgIssue(b, tp1);
      }
      asm volatile("" ::: "memory");

      if (lane == 63) {
        __hip_atomic_store(h_ring + ((size_t)((t + 4) & 7) * B_SZ + b) * 512 + (col0 >> 1),
                           POIS, __ATOMIC_RELAXED, __HIP_MEMORY_SCOPE_AGENT);
        float z0 = __builtin_amdgcn_rcpf(1.0f + __expf(-(xz.x + s0 + bz0)));
        float z1 = __builtin_amdgcn_rcpf(1.0f + __expf(-(xz.y + s1 + bz1)));
        float r0 = __builtin_amdgcn_rcpf(1.0f + __expf(-(xr.x + s2 + br0)));
        float r1 = __builtin_amdgcn_rcpf(1.0f + __expf(-(xr.y + s3 + br1)));
        float a0 = xh.x + r0 * (s4 + bq0);
        float a1 = xh.y + r1 * (s5 + bq1);
        float e0 = __expf(-2.0f * fabsf(a0));
        float e1 = __expf(-2.0f * fabsf(a1));
        float hc0 = copysignf((1.0f - e0) * __builtin_amdgcn_rcpf(1.0f + e0), a0);
        float hc1 = copysignf((1.0f - e1) * __builtin_amdgcn_rcpf(1.0f + e1), a1);
        float h0 = z0 * hold0[b] + (1.0f - z0) * hc0;
        float h1 = z1 * hold1[b] + (1.0f - z1) * hc1;
        hold0[b] = h0; hold1[b] = h1;
        u64 hv = ((u64)__float_as_uint(h1) << 32) | (u64)__float_as_uint(h0);
        __hip_atomic_store(h_ring + ((size_t)((t + 1) & 7) * B_SZ + b) * 512 + (col0 >> 1),
                           hv, __ATOMIC_RELAXED, __HIP_MEMORY_SCOPE_AGENT);
        // hs output: write-through 4B atomics (IC-visible for in-kernel consumer)
        size_t hidx = ((size_t)b * S_SZ + t) * U_SZ + col0;
        f16 h0h = (f16)h0, h1h = (f16)h1;
        f16x2 hi2; hi2[0] = h0h; hi2[1] = h1h;
        f16x2 lo2;
        lo2[0] = (f16)((h0 - (float)h0h) * 4096.0f);
        lo2[1] = (f16)((h1 - (float)h1h) * 4096.0f);
        unsigned uhi, ulo;
        __builtin_memcpy(&uhi, &hi2, 4);
        __builtin_memcpy(&ulo, &lo2, 4);
        __hip_atomic_store((unsigned*)(hs_hi + hidx), uhi,
                           __ATOMIC_RELAXED, __HIP_MEMORY_SCOPE_AGENT);
        __hip_atomic_store((unsigned*)(hs_lo + hidx), ulo,
                           __ATOMIC_RELAXED, __HIP_MEMORY_SCOPE_AGENT);
        if ((t & 127) == 127) {        // block boundary: release hs block
          asm volatile("s_waitcnt vmcnt(0)" ::: "memory");
          __hip_atomic_fetch_add(&cnt[(((unsigned)t >> 7) << 2) | (unsigned)b], 1u,
                                 __ATOMIC_RELAXED, __HIP_MEMORY_SCOPE_AGENT);
        }
      }
    }
  }
}

__device__ __forceinline__ void gemm_role(char* smem, int* sh_tile,
    const f16* __restrict__ Ah, const f16* __restrict__ Al,
    const f16* __restrict__ Bt, const float* __restrict__ bd,
    float* __restrict__ out, unsigned* __restrict__ cnt, unsigned* __restrict__ ttix) {
  f16 (*lds)[3 * 4096] = (f16(*)[3 * 4096])smem;   // 48 KB
  const int tid = threadIdx.x;
  const int lane = tid & 63;
  const int wave = tid >> 6;
  const int wm = wave >> 1, wn = wave & 1;

  for (;;) {
    __syncthreads();                   // protect sh_tile reuse
    if (tid == 0)
      *sh_tile = (int)__hip_atomic_fetch_add(ttix, 1u, __ATOMIC_RELAXED,
                                             __HIP_MEMORY_SCOPE_AGENT);
    __syncthreads();
    const int tile = *sh_tile;
    if (tile >= NTILES) break;
    const int g = tile / 250;
    const int n0 = (tile % 250) * 128;
    if (tid == 0) {                    // ready-poll (agent atomic = IC-coherent)
      while (__hip_atomic_load(&cnt[g], __ATOMIC_RELAXED, __HIP_MEMORY_SCOPE_AGENT) < 512u)
        __builtin_amdgcn_s_sleep(10);
    }
    __syncthreads();
    const int m0 = (g & 3) * S_SZ + (g >> 2) * 128;

    f32x4 accH[4][4] = {};
    f32x4 accL[4][4] = {};
    f32x4 areg[4];
    auto issueA = [&](int kk) {        // sc0sc1 reg-stage (bypass -> never stale)
#pragma unroll
      for (int i = 0; i < 4; ++i) {
        int gg = i * 256 + tid;
        int idx = gg & 511, r = idx >> 2;
        int kg = (idx & 3) ^ ((r >> 1) & 3);
        const f16* src = (gg >> 9) ? Al : Ah;
        const f16* gp = src + (size_t)(m0 + r) * 1024 + kk + kg * 8;
        asm volatile("global_load_dwordx4 %0, %1, off sc0 sc1"
                     : "=&v"(areg[i]) : "v"(gp) : "memory");
      }
    };
    auto issueB = [&](int buf, int kk) {
#pragma unroll
      for (int i = 4; i < 6; ++i) {
        int gg = i * 256 + tid;
        int idx = gg & 511, r = idx >> 2;
        int kg = (idx & 3) ^ ((r >> 1) & 3);
        const f16* gp = Bt + (size_t)(n0 + r) * 1024 + kk + kg * 8;
        f16* lp = &lds[buf][(gg & ~63) * 8];
        async_copy16(gp, lp);
      }
    };
    auto writeA = [&](int buf) {
#pragma unroll
      for (int i = 0; i < 4; ++i) {
        int gg = i * 256 + tid;
        *(f32x4*)&lds[buf][gg * 8] = areg[i];
      }
    };

    issueA(0); issueB(0, 0);
    asm volatile("s_waitcnt vmcnt(2)" ::: "memory");   // A retired; B may ride
    writeA(0);
    int buf = 0;
    for (int kk = 0; kk < 1024; kk += 32) {
      __syncthreads();                 // buf ready
      const bool more = (kk + 32 < 1024);
      if (more) { issueA(kk + 32); issueB(buf ^ 1, kk + 32); }
      const f16* base = &lds[buf][0];
      const int kgl = lane >> 4;
      f16x8 bfr[4];
#pragma unroll
      for (int fn = 0; fn < 4; ++fn) {
        int r = wn * 64 + fn * 16 + (lane & 15);
        bfr[fn] = *(const f16x8*)(base + 2 * 4096 + r * 32 + ((kgl ^ ((r >> 1) & 3)) * 8));
      }
#pragma unroll
      for (int fm = 0; fm < 4; ++fm) {
        int r = wm * 64 + fm * 16 + (lane & 15);
        int off = r * 32 + ((kgl ^ ((r >> 1) & 3)) * 8);
        f16x8 ah = *(const f16x8*)(base + off);
        f16x8 al = *(const f16x8*)(base + 4096 + off);
#pragma unroll
        for (int fn = 0; fn < 4; ++fn) {
          accH[fm][fn] = mfma16(ah, bfr[fn], accH[fm][fn]);
          accL[fm][fn] = mfma16(al, bfr[fn], accL[fm][fn]);
        }
      }
      if (more) {
        asm volatile("s_waitcnt vmcnt(2)" ::: "memory");  // this iter's A retired
        writeA(buf ^ 1);
      }
      buf ^= 1;
    }
    const float inv = 1.0f / 4096.0f;
#pragma unroll
    for (int fn = 0; fn < 4; ++fn) {
      int col = n0 + wn * 64 + fn * 16 + (lane & 15);
      float bv = bd[col];
#pragma unroll
      for (int fm = 0; fm < 4; ++fm) {
        int row0 = m0 + wm * 64 + fm * 16 + ((lane >> 4) << 2);
#pragma unroll
        for (int j = 0; j < 4; ++j)
          out[(size_t)(row0 + j) * V_SZ + col] = accH[fm][fn][j] + inv * accL[fm][fn][j] + bv;
      }
    }
  }
}

__global__ __launch_bounds__(256, 1)
void k_fused(const float* __restrict__ xg, const float* __restrict__ Wh,
             const float* __restrict__ bh, u64* __restrict__ h_ring,
             f16* __restrict__ hs_hi, f16* __restrict__ hs_lo,
             const f16* __restrict__ Wd_t, const float* __restrict__ bd,
             float* __restrict__ out, unsigned* __restrict__ cnt,
             unsigned* __restrict__ tix) {
  __shared__ __align__(16) char smem[49152];
  __shared__ int sh_role;
  __shared__ int sh_tile;
  if (threadIdx.x == 0)
    sh_role = (int)__hip_atomic_fetch_add(&tix[0], 1u, __ATOMIC_RELAXED,
                                          __HIP_MEMORY_SCOPE_AGENT);
  __syncthreads();
  const int role = sh_role;
  if (role < NGRU)
    gru_role(role, smem, xg, Wh, bh, h_ring, hs_hi, hs_lo, cnt);
  else
    gemm_role(smem, &sh_tile, hs_hi, hs_lo, Wd_t, bd, out, cnt, &tix[1]);
}

// ---------------- launch ----------------
extern "C" void kernel_launch(void* const* d_in, const int* in_sizes, int n_in,
                              void* d_out, int out_size, void* d_ws, size_t ws_size,
                              hipStream_t stream) {
  const int*   inputs = (const int*)d_in[0];
  const float* emb    = (const float*)d_in[1];
  const float* Wx     = (const float*)d_in[2];
  const float* Wh     = (const float*)d_in[3];
  const float* bx     = (const float*)d_in[4];
  const float* bh     = (const float*)d_in[5];
  const float* Wd     = (const float*)d_in[6];
  const float* bd     = (const float*)d_in[7];
  float* out = (float*)d_out;

  char* ws = (char*)d_ws;
  // layout (bytes), all 256-aligned
  f16*   x_hi  = (f16*)(ws + 0);            //  8,388,608
  f16*   x_lo  = (f16*)(ws + 8388608);      //  8,388,608
  f16*   Wx_t  = (f16*)(ws + 16777216);     //  3,145,728  [3072][512]
  f16*   Wd_t  = (f16*)(ws + 19922944);     // 65,536,000  [32000][1024]
  f16*   hs_hi = (f16*)(ws + 85458944);     // 16,777,216  [B*S][1024]
  f16*   hs_lo = (f16*)(ws + 102236160);    // 16,777,216
  float* xg    = (float*)(ws + 119013376);  // 100,663,296 [S][B][3072]
  u64*   h_ring = (u64*)(ws + 219676672);   // 131,072     [8][4][1024] fp32
  unsigned* cnt = (unsigned*)(ws + 219807744);  // 256  [64]
  unsigned* tix = (unsigned*)(ws + 219808000);  // 8    [role, tile]

  // per-call init (graph-replay safe): ring slot0=zeros, slots1-7=-NaN; cnt/tix=0
  hipMemsetAsync(ws + 219676672, 0x00, 16384, stream);
  hipMemsetAsync(ws + 219676672 + 16384, 0xFF, 114688, stream);
  hipMemsetAsync(ws + 219807744, 0x00, 512, stream);

  k_gather_split<<<B_SZ * S_SZ, 128, 0, stream>>>(inputs, emb, x_hi, x_lo);
  k_transpose_split<<<dim3(3072 / 32, 512 / 32), 256, 0, stream>>>(Wx, Wx_t, 512, 3072);
  k_transpose_split<<<dim3(V_SZ / 32, 1024 / 32), 256, 0, stream>>>(Wd, Wd_t, 1024, V_SZ);
  k_gemm2s<512, true><<<dim3(3072 / 128, 8192 / 128), 256, 0, stream>>>(
      x_hi, x_lo, Wx_t, bx, xg, 3072);
  k_fused<<<GRID_FUSED, 256, 0, stream>>>(xg, Wh, bh, h_ring, hs_hi, hs_lo,
                                          Wd_t, bd, out, cnt, tix);
}

// Round 12
// 8953.571 us; speedup vs baseline: 1.7416x; 1.0055x over previous
//
#include <hip/hip_runtime.h>
#include <hip/hip_bf16.h>
#include <cstdint>
#include <cstddef>

#define V_SZ 32000
#define E_SZ 512
#define U_SZ 1024
#define B_SZ 4
#define S_SZ 2048
#define NGRU 128      // GRU roles: 128 WGs x 256 thr = 512 waves; wave owns 2 h-cols
#define NTILES 16000  // logits tiles: 64 (tblk,b) groups x 250 n-tiles
#define GRID_FUSED 256  // == CU count: 1 WG/CU, GRU and GEMM spatially partitioned

typedef _Float16 f16;
typedef _Float16 f16x2 __attribute__((ext_vector_type(2)));
typedef _Float16 f16x8 __attribute__((ext_vector_type(8)));
typedef _Float16 f16x4 __attribute__((ext_vector_type(4)));
typedef float    f32x4 __attribute__((ext_vector_type(4)));
typedef unsigned long long u64;

__device__ __forceinline__ void async_copy16(const void* g, void* l) {
  __builtin_amdgcn_global_load_lds(
      (const __attribute__((address_space(1))) void*)g,
      (__attribute__((address_space(3))) void*)l, 16, 0, 0);
}

__device__ __forceinline__ f32x4 mfma16(f16x8 a, f16x8 b, f32x4 c) {
  return __builtin_amdgcn_mfma_f32_16x16x32_f16(a, b, c, 0, 0, 0);
}

// full-wave (64) sum via DPP; result valid in lane 63 only. Pure VALU.
__device__ __forceinline__ float wave_sum64(float v) {
  v += __int_as_float(__builtin_amdgcn_update_dpp(0, __float_as_int(v), 0x111, 0xf, 0xf, true)); // row_shr:1
  v += __int_as_float(__builtin_amdgcn_update_dpp(0, __float_as_int(v), 0x112, 0xf, 0xf, true)); // row_shr:2
  v += __int_as_float(__builtin_amdgcn_update_dpp(0, __float_as_int(v), 0x114, 0xf, 0xf, true)); // row_shr:4
  v += __int_as_float(__builtin_amdgcn_update_dpp(0, __float_as_int(v), 0x118, 0xf, 0xf, true)); // row_shr:8
  v += __int_as_float(__builtin_amdgcn_update_dpp(0, __float_as_int(v), 0x142, 0xa, 0xf, true)); // row_bcast:15
  v += __int_as_float(__builtin_amdgcn_update_dpp(0, __float_as_int(v), 0x143, 0xc, 0xf, true)); // row_bcast:31
  return v;
}

// ---------------- embedding gather + hi/lo fp16 split ----------------
__global__ void k_gather_split(const int* __restrict__ inputs, const float* __restrict__ emb,
                               f16* __restrict__ x_hi, f16* __restrict__ x_lo) {
  int m = blockIdx.x;                  // 8192 rows, m = b*2048 + s
  int row = inputs[m];
  const float* src = emb + (size_t)row * E_SZ;
  int j = threadIdx.x * 4;
  f32x4 v = *(const f32x4*)(src + j);
  f16x4 hi, lo;
#pragma unroll
  for (int q = 0; q < 4; ++q) {
    f16 h = (f16)v[q];
    hi[q] = h;
    lo[q] = (f16)((v[q] - (float)h) * 4096.0f);
  }
  *(f16x4*)(x_hi + (size_t)m * E_SZ + j) = hi;
  *(f16x4*)(x_lo + (size_t)m * E_SZ + j) = lo;
}

// ---------------- transpose [K][N] fp32 -> [N][K] fp16 ----------------
__global__ void k_transpose_split(const float* __restrict__ W, f16* __restrict__ Wt,
                                  int K, int N) {
  __shared__ float tile[32][33];
  int tx = threadIdx.x & 31, ty = threadIdx.x >> 5;   // 32 x 8
  int n0 = blockIdx.x * 32, k0 = blockIdx.y * 32;
#pragma unroll
  for (int i = 0; i < 4; ++i)
    tile[ty + 8 * i][tx] = W[(size_t)(k0 + ty + 8 * i) * N + n0 + tx];
  __syncthreads();
#pragma unroll
  for (int i = 0; i < 4; ++i)
    Wt[(size_t)(n0 + ty + 8 * i) * K + k0 + tx] = (f16)tile[tx][ty + 8 * i];
}

// ---------------- fp16 2-pass GEMM (xg only): C = (Ah+Al/4096)@Bt^T + bias -------
template<int K, bool REMAP>
__global__ __launch_bounds__(256, 2)
void k_gemm2s(const f16* __restrict__ Ah, const f16* __restrict__ Al,
              const f16* __restrict__ Bt, const float* __restrict__ bias,
              float* __restrict__ C, int N) {
  __shared__ f16 lds[2][3 * 4096];
  const int tid = threadIdx.x;
  const int lane = tid & 63;
  const int wave = tid >> 6;
  const int wm = wave >> 1, wn = wave & 1;
  const int m0 = blockIdx.y * 128;
  const int n0 = blockIdx.x * 128;

  auto stage = [&](int buf, int kk) {
#pragma unroll
    for (int i = 0; i < 6; ++i) {
      int g = i * 256 + tid;
      int tile = g >> 9;
      int idx = g & 511;
      int r = idx >> 2;
      int kg = (idx & 3) ^ ((r >> 1) & 3);
      const f16* src = (tile == 0) ? Ah : (tile == 1) ? Al : Bt;
      int row = (tile == 2) ? (n0 + r) : (m0 + r);
      const f16* gp = src + (size_t)row * K + kk + kg * 8;
      f16* lp = &lds[buf][(g & ~63) * 8];
      async_copy16(gp, lp);
    }
  };

  f32x4 accH[4][4] = {};
  f32x4 accL[4][4] = {};
  stage(0, 0);
  int buf = 0;
  for (int kk = 0; kk < K; kk += 32) {
    __syncthreads();
    if (kk + 32 < K) stage(buf ^ 1, kk + 32);
    const f16* base = &lds[buf][0];
    const int kg = lane >> 4;
    f16x8 bfr[4];
#pragma unroll
    for (int fn = 0; fn < 4; ++fn) {
      int r = wn * 64 + fn * 16 + (lane & 15);
      bfr[fn] = *(const f16x8*)(base + 2 * 4096 + r * 32 + ((kg ^ ((r >> 1) & 3)) * 8));
    }
#pragma unroll
    for (int fm = 0; fm < 4; ++fm) {
      int r = wm * 64 + fm * 16 + (lane & 15);
      int off = r * 32 + ((kg ^ ((r >> 1) & 3)) * 8);
      f16x8 ah = *(const f16x8*)(base + off);
      f16x8 al = *(const f16x8*)(base + 4096 + off);
#pragma unroll
      for (int fn = 0; fn < 4; ++fn) {
        accH[fm][fn] = mfma16(ah, bfr[fn], accH[fm][fn]);
        accL[fm][fn] = mfma16(al, bfr[fn], accL[fm][fn]);
      }
    }
    buf ^= 1;
  }
  const float inv = 1.0f / 4096.0f;
#pragma unroll
  for (int fn = 0; fn < 4; ++fn) {
    int col = n0 + wn * 64 + fn * 16 + (lane & 15);
    float bv = bias[col];
#pragma unroll
    for (int fm = 0; fm < 4; ++fm) {
      int row0 = m0 + wm * 64 + fm * 16 + ((lane >> 4) << 2);
#pragma unroll
      for (int j = 0; j < 4; ++j) {
        int row = row0 + j;
        float v = accH[fm][fn][j] + inv * accL[fm][fn][j] + bv;
        size_t orow = REMAP ? ((size_t)(row & (S_SZ - 1)) * B_SZ + (row >> 11))
                            : (size_t)row;
        C[orow * (size_t)N + col] = v;
      }
    }
  }
}

// ================= fused persistent kernel: GRU roles + logits-GEMM roles =========
// grid = 256 = CU count -> 1 WG/CU, co-resident: GRU roles (tickets 0..127) own 128
// CUs with ZERO SIMD co-tenancy; 128 GEMM workers own the other 128 CUs and steal
// tiles in ready-order. Handshake (round-10/11-proven): hs = relaxed agent 4B
// atomic stores (IC write-through); at t%128==127 lane63 vmcnt(0)+fetch_add(cnt);
// worker polls cnt[g]==512, reg-stages A via sc0sc1 (bypass -> no stale L2), B via
// global_load_lds. NEW (round 12): out stores are NON-TEMPORAL (nt) -> the 1.05 GB
// out stream no longer write-allocates in the IC, keeping Wd_t (64MB) IC-resident
// (was being evicted ~39x = 2.4GB HBM re-fetch + IC port pressure on GRU polls).

__device__ __forceinline__ void gru_role(int role, char* smem,
    const float* __restrict__ xg, const float* __restrict__ Wh,
    const float* __restrict__ bh, u64* __restrict__ h_ring,
    f16* __restrict__ hs_hi, f16* __restrict__ hs_lo, unsigned* __restrict__ cnt) {
  float (*Whs)[1028] = (float(*)[1028])smem;   // staging only (init), 32.9 KB
  const int tid = threadIdx.x;
  const int lane = tid & 63;
  const int wave = tid >> 6;
  const int u0 = role * 8;             // WG's 8 cols
  const int col0 = u0 + wave * 2;

  // ---- stage Wh into registers: Wreg order [z0,z1,r0,r1,h0,h1] ----
  f32x4 Wreg[6][4];
  for (int gate = 0; gate < 3; ++gate) {
    __syncthreads();
    for (int idx = tid; idx < 8 * 1024; idx += 256) {
      int j = idx & 7, k = idx >> 3;
      Whs[j][k] = Wh[(size_t)k * 3072 + gate * 1024 + u0 + j];
    }
    __syncthreads();
#pragma unroll
    for (int cj = 0; cj < 2; ++cj)
#pragma unroll
      for (int i = 0; i < 4; ++i)
        Wreg[gate * 2 + cj][i] = *(const f32x4*)&Whs[wave * 2 + cj][i * 256 + lane * 4];
  }
  __builtin_amdgcn_s_setprio(1);

  const float bz0 = bh[col0],        bz1 = bh[col0 + 1];
  const float br0 = bh[1024 + col0], br1 = bh[1024 + col0 + 1];
  const float bq0 = bh[2048 + col0], bq1 = bh[2048 + col0 + 1];
  float hold0[4] = {0.f, 0.f, 0.f, 0.f};
  float hold1[4] = {0.f, 0.f, 0.f, 0.f};
  const u64 POIS = 0xFFFFFFFFFFFFFFFFull;

  u64 q[8];
  const u64* pbase;
  auto pollLoads = [&]() {
#pragma unroll
    for (int i = 0; i < 4; ++i) {
      q[2 * i]     = __hip_atomic_load(pbase + i * 128 + 2 * lane,
                                       __ATOMIC_RELAXED, __HIP_MEMORY_SCOPE_AGENT);
      q[2 * i + 1] = __hip_atomic_load(pbase + i * 128 + 2 * lane + 1,
                                       __ATOMIC_RELAXED, __HIP_MEMORY_SCOPE_AGENT);
    }
  };
  auto issue = [&](int slot, int row) {
    pbase = h_ring + ((size_t)slot * B_SZ + row) * 512;
    pollLoads();
  };
  float2 xzv[4], xrv[4], xhv[4];
  auto xgIssue = [&](int b2, int t2) {
    const float* p = xg + ((size_t)t2 * B_SZ + b2) * 3072 + col0;
    xzv[b2] = *(const float2*)p;
    xrv[b2] = *(const float2*)(p + 1024);
    xhv[b2] = *(const float2*)(p + 2048);
  };

  issue(0, 0);
  xgIssue(0, 0); xgIssue(1, 0); xgIssue(2, 0); xgIssue(3, 0);

  for (int t = 0; t < S_SZ; ++t) {
#pragma unroll
    for (int b = 0; b < 4; ++b) {
      const float2 xz = xzv[b], xr = xrv[b], xh = xhv[b];
      // peeled fast-path check (counted wait); retry is the rare path
      {
        bool ok = (q[0] != POIS) && (q[1] != POIS) && (q[2] != POIS) && (q[3] != POIS)
               && (q[4] != POIS) && (q[5] != POIS) && (q[6] != POIS) && (q[7] != POIS);
        if (!__all(ok)) {
          while (true) {
            __builtin_amdgcn_s_sleep(1);
            pollLoads();
            bool ok2 = (q[0] != POIS) && (q[1] != POIS) && (q[2] != POIS) && (q[3] != POIS)
                    && (q[4] != POIS) && (q[5] != POIS) && (q[6] != POIS) && (q[7] != POIS);
            if (__all(ok2)) break;
          }
        }
      }
      float hp[16];
#pragma unroll
      for (int j2 = 0; j2 < 8; ++j2) {
        hp[2 * j2]     = __uint_as_float((unsigned int)q[j2]);
        hp[2 * j2 + 1] = __uint_as_float((unsigned int)(q[j2] >> 32));
      }
      float a6[6];
#pragma unroll
      for (int c = 0; c < 6; ++c) {
        float v = 0.0f;
#pragma unroll
        for (int i = 0; i < 4; ++i)
#pragma unroll
          for (int qq = 0; qq < 4; ++qq)
            v += Wreg[c][i][qq] * hp[4 * i + qq];
        a6[c] = v;
      }
      float s0 = wave_sum64(a6[0]), s1 = wave_sum64(a6[1]), s2 = wave_sum64(a6[2]);
      float s3 = wave_sum64(a6[3]), s4 = wave_sum64(a6[4]), s5 = wave_sum64(a6[5]);

      // issue next-slice polls + next-step xg BEFORE stores (drain hygiene, v8)
      asm volatile("" ::: "memory");
      {
        const int nb = (b + 1) & 3;
        const int nt = (b == 3) ? (t + 1) : t;
        issue(nt & 7, nb);
        const int tp1 = (t + 1 < S_SZ) ? (t + 1) : (S_SZ - 1);
        xgIssue(b, tp1);
      }
      asm volatile("" ::: "memory");

      if (lane == 63) {
        __hip_atomic_store(h_ring + ((size_t)((t + 4) & 7) * B_SZ + b) * 512 + (col0 >> 1),
                           POIS, __ATOMIC_RELAXED, __HIP_MEMORY_SCOPE_AGENT);
        float z0 = __builtin_amdgcn_rcpf(1.0f + __expf(-(xz.x + s0 + bz0)));
        float z1 = __builtin_amdgcn_rcpf(1.0f + __expf(-(xz.y + s1 + bz1)));
        float r0 = __builtin_amdgcn_rcpf(1.0f + __expf(-(xr.x + s2 + br0)));
        float r1 = __builtin_amdgcn_rcpf(1.0f + __expf(-(xr.y + s3 + br1)));
        float a0 = xh.x + r0 * (s4 + bq0);
        float a1 = xh.y + r1 * (s5 + bq1);
        float e0 = __expf(-2.0f * fabsf(a0));
        float e1 = __expf(-2.0f * fabsf(a1));
        float hc0 = copysignf((1.0f - e0) * __builtin_amdgcn_rcpf(1.0f + e0), a0);
        float hc1 = copysignf((1.0f - e1) * __builtin_amdgcn_rcpf(1.0f + e1), a1);
        float h0 = z0 * hold0[b] + (1.0f - z0) * hc0;
        float h1 = z1 * hold1[b] + (1.0f - z1) * hc1;
        hold0[b] = h0; hold1[b] = h1;
        u64 hv = ((u64)__float_as_uint(h1) << 32) | (u64)__float_as_uint(h0);
        __hip_atomic_store(h_ring + ((size_t)((t + 1) & 7) * B_SZ + b) * 512 + (col0 >> 1),
                           hv, __ATOMIC_RELAXED, __HIP_MEMORY_SCOPE_AGENT);
        // hs output: write-through 4B atomics (IC-visible for in-kernel consumer)
        size_t hidx = ((size_t)b * S_SZ + t) * U_SZ + col0;
        f16 h0h = (f16)h0, h1h = (f16)h1;
        f16x2 hi2; hi2[0] = h0h; hi2[1] = h1h;
        f16x2 lo2;
        lo2[0] = (f16)((h0 - (float)h0h) * 4096.0f);
        lo2[1] = (f16)((h1 - (float)h1h) * 4096.0f);
        unsigned uhi, ulo;
        __builtin_memcpy(&uhi, &hi2, 4);
        __builtin_memcpy(&ulo, &lo2, 4);
        __hip_atomic_store((unsigned*)(hs_hi + hidx), uhi,
                           __ATOMIC_RELAXED, __HIP_MEMORY_SCOPE_AGENT);
        __hip_atomic_store((unsigned*)(hs_lo + hidx), ulo,
                           __ATOMIC_RELAXED, __HIP_MEMORY_SCOPE_AGENT);
        if ((t & 127) == 127) {        // block boundary: release hs block
          asm volatile("s_waitcnt vmcnt(0)" ::: "memory");
          __hip_atomic_fetch_add(&cnt[(((unsigned)t >> 7) << 2) | (unsigned)b], 1u,
                                 __ATOMIC_RELAXED, __HIP_MEMORY_SCOPE_AGENT);
        }
      }
    }
  }
}

__device__ __forceinline__ void gemm_role(char* smem, int* sh_tile,
    const f16* __restrict__ Ah, const f16* __restrict__ Al,
    const f16* __restrict__ Bt, const float* __restrict__ bd,
    float* __restrict__ out, unsigned* __restrict__ cnt, unsigned* __restrict__ ttix) {
  f16 (*lds)[3 * 4096] = (f16(*)[3 * 4096])smem;   // 48 KB
  const int tid = threadIdx.x;
  const int lane = tid & 63;
  const int wave = tid >> 6;
  const int wm = wave >> 1, wn = wave & 1;

  for (;;) {
    __syncthreads();                   // protect sh_tile reuse
    if (tid == 0)
      *sh_tile = (int)__hip_atomic_fetch_add(ttix, 1u, __ATOMIC_RELAXED,
                                             __HIP_MEMORY_SCOPE_AGENT);
    __syncthreads();
    const int tile = *sh_tile;
    if (tile >= NTILES) break;
    const int g = tile / 250;
    const int n0 = (tile % 250) * 128;
    if (tid == 0) {                    // ready-poll (agent atomic = IC-coherent)
      while (__hip_atomic_load(&cnt[g], __ATOMIC_RELAXED, __HIP_MEMORY_SCOPE_AGENT) < 512u)
        __builtin_amdgcn_s_sleep(10);
    }
    __syncthreads();
    const int m0 = (g & 3) * S_SZ + (g >> 2) * 128;

    f32x4 accH[4][4] = {};
    f32x4 accL[4][4] = {};
    f32x4 areg[4];
    auto issueA = [&](int kk) {        // sc0sc1 reg-stage (bypass -> never stale)
#pragma unroll
      for (int i = 0; i < 4; ++i) {
        int gg = i * 256 + tid;
        int idx = gg & 511, r = idx >> 2;
        int kg = (idx & 3) ^ ((r >> 1) & 3);
        const f16* src = (gg >> 9) ? Al : Ah;
        const f16* gp = src + (size_t)(m0 + r) * 1024 + kk + kg * 8;
        asm volatile("global_load_dwordx4 %0, %1, off sc0 sc1"
                     : "=&v"(areg[i]) : "v"(gp) : "memory");
      }
    };
    auto issueB = [&](int buf, int kk) {
#pragma unroll
      for (int i = 4; i < 6; ++i) {
        int gg = i * 256 + tid;
        int idx = gg & 511, r = idx >> 2;
        int kg = (idx & 3) ^ ((r >> 1) & 3);
        const f16* gp = Bt + (size_t)(n0 + r) * 1024 + kk + kg * 8;
        f16* lp = &lds[buf][(gg & ~63) * 8];
        async_copy16(gp, lp);
      }
    };
    auto writeA = [&](int buf) {
#pragma unroll
      for (int i = 0; i < 4; ++i) {
        int gg = i * 256 + tid;
        *(f32x4*)&lds[buf][gg * 8] = areg[i];
      }
    };

    issueA(0); issueB(0, 0);
    asm volatile("s_waitcnt vmcnt(2)" ::: "memory");   // A retired; B may ride
    writeA(0);
    int buf = 0;
    for (int kk = 0; kk < 1024; kk += 32) {
      __syncthreads();                 // buf ready
      const bool more = (kk + 32 < 1024);
      if (more) { issueA(kk + 32); issueB(buf ^ 1, kk + 32); }
      const f16* base = &lds[buf][0];
      const int kgl = lane >> 4;
      f16x8 bfr[4];
#pragma unroll
      for (int fn = 0; fn < 4; ++fn) {
        int r = wn * 64 + fn * 16 + (lane & 15);
        bfr[fn] = *(const f16x8*)(base + 2 * 4096 + r * 32 + ((kgl ^ ((r >> 1) & 3)) * 8));
      }
#pragma unroll
      for (int fm = 0; fm < 4; ++fm) {
        int r = wm * 64 + fm * 16 + (lane & 15);
        int off = r * 32 + ((kgl ^ ((r >> 1) & 3)) * 8);
        f16x8 ah = *(const f16x8*)(base + off);
        f16x8 al = *(const f16x8*)(base + 4096 + off);
#pragma unroll
        for (int fn = 0; fn < 4; ++fn) {
          accH[fm][fn] = mfma16(ah, bfr[fn], accH[fm][fn]);
          accL[fm][fn] = mfma16(al, bfr[fn], accL[fm][fn]);
        }
      }
      if (more) {
        asm volatile("s_waitcnt vmcnt(2)" ::: "memory");  // this iter's A retired
        writeA(buf ^ 1);
      }
      buf ^= 1;
    }
    const float inv = 1.0f / 4096.0f;
#pragma unroll
    for (int fn = 0; fn < 4; ++fn) {
      int col = n0 + wn * 64 + fn * 16 + (lane & 15);
      float bv = bd[col];
#pragma unroll
      for (int fm = 0; fm < 4; ++fm) {
        int row0 = m0 + wm * 64 + fm * 16 + ((lane >> 4) << 2);
#pragma unroll
        for (int j = 0; j < 4; ++j) {
          float v = accH[fm][fn][j] + inv * accL[fm][fn][j] + bv;
          float* p = out + (size_t)(row0 + j) * V_SZ + col;
          // non-temporal: out is never re-read in-kernel; don't evict Wd_t from IC
          asm volatile("global_store_dword %0, %1, off nt" :: "v"(p), "v"(v) : "memory");
        }
      }
    }
  }
}

__global__ __launch_bounds__(256, 1)
void k_fused(const float* __restrict__ xg, const float* __restrict__ Wh,
             const float* __restrict__ bh, u64* __restrict__ h_ring,
             f16* __restrict__ hs_hi, f16* __restrict__ hs_lo,
             const f16* __restrict__ Wd_t, const float* __restrict__ bd,
             float* __restrict__ out, unsigned* __restrict__ cnt,
             unsigned* __restrict__ tix) {
  __shared__ __align__(16) char smem[49152];
  __shared__ int sh_role;
  __shared__ int sh_tile;
  if (threadIdx.x == 0)
    sh_role = (int)__hip_atomic_fetch_add(&tix[0], 1u, __ATOMIC_RELAXED,
                                          __HIP_MEMORY_SCOPE_AGENT);
  __syncthreads();
  const int role = sh_role;
  if (role < NGRU)
    gru_role(role, smem, xg, Wh, bh, h_ring, hs_hi, hs_lo, cnt);
  else
    gemm_role(smem, &sh_tile, hs_hi, hs_lo, Wd_t, bd, out, cnt, &tix[1]);
}

// ---------------- launch ----------------
extern "C" void kernel_launch(void* const* d_in, const int* in_sizes, int n_in,
                              void* d_out, int out_size, void* d_ws, size_t ws_size,
                              hipStream_t stream) {
  const int*   inputs = (const int*)d_in[0];
  const float* emb    = (const float*)d_in[1];
  const float* Wx     = (const float*)d_in[2];
  const float* Wh     = (const float*)d_in[3];
  const float* bx     = (const float*)d_in[4];
  const float* bh     = (const float*)d_in[5];
  const float* Wd     = (const float*)d_in[6];
  const float* bd     = (const float*)d_in[7];
  float* out = (float*)d_out;

  char* ws = (char*)d_ws;
  // layout (bytes), all 256-aligned
  f16*   x_hi  = (f16*)(ws + 0);            //  8,388,608
  f16*   x_lo  = (f16*)(ws + 8388608);      //  8,388,608
  f16*   Wx_t  = (f16*)(ws + 16777216);     //  3,145,728  [3072][512]
  f16*   Wd_t  = (f16*)(ws + 19922944);     // 65,536,000  [32000][1024]
  f16*   hs_hi = (f16*)(ws + 85458944);     // 16,777,216  [B*S][1024]
  f16*   hs_lo = (f16*)(ws + 102236160);    // 16,777,216
  float* xg    = (float*)(ws + 119013376);  // 100,663,296 [S][B][3072]
  u64*   h_ring = (u64*)(ws + 219676672);   // 131,072     [8][4][1024] fp32
  unsigned* cnt = (unsigned*)(ws + 219807744);  // 256  [64]
  unsigned* tix = (unsigned*)(ws + 219808000);  // 8    [role, tile]

  // per-call init (graph-replay safe): ring slot0=zeros, slots1-7=-NaN; cnt/tix=0
  hipMemsetAsync(ws + 219676672, 0x00, 16384, stream);
  hipMemsetAsync(ws + 219676672 + 16384, 0xFF, 114688, stream);
  hipMemsetAsync(ws + 219807744, 0x00, 512, stream);

  k_gather_split<<<B_SZ * S_SZ, 128, 0, stream>>>(inputs, emb, x_hi, x_lo);
  k_transpose_split<<<dim3(3072 / 32, 512 / 32), 256, 0, stream>>>(Wx, Wx_t, 512, 3072);
  k_transpose_split<<<dim3(V_SZ / 32, 1024 / 32), 256, 0, stream>>>(Wd, Wd_t, 1024, V_SZ);
  k_gemm2s<512, true><<<dim3(3072 / 128, 8192 / 128), 256, 0, stream>>>(
      x_hi, x_lo, Wx_t, bx, xg, 3072);
  k_fused<<<GRID_FUSED, 256, 0, stream>>>(xg, Wh, bh, h_ring, hs_hi, hs_lo,
                                          Wd_t, bd, out, cnt, tix);
}